// Round 4
// baseline (291.854 us; speedup 1.0000x reference)
//
#include <hip/hip_runtime.h>
#include <math.h>

#define HOP     256
#define CUTOFF  513
#define NMELS   80
#define BATCH   16
#define LEN     524288
#define NFRAMES 2049
#define NFFT    1024
#define KW      48              // max packed mel-filter width (analytic max 37; margin 11)
#define WSTRIDE 49              // odd LDS row stride -> conflict-free weight reads
#define TBLK    16              // frames per block (8 pair-FFTs)

// FFT LDS anti-bank-conflict padding: one extra float2 per 16
#define ZIDX(i) ((i) + ((i) >> 4))

__device__ __forceinline__ float2 cmul(float2 a, float2 b) {
    return make_float2(a.x * b.x - a.y * b.y, a.x * b.y + a.y * b.x);
}

// ---------------------------------------------------------------------------
// Kernel 0a: twiddle + window tables (d_ws is re-poisoned before every launch,
// so these must be rebuilt each call; ~1 us).
// tw[k] = e^{-2 pi i k/1024}, k<512 ; win = periodic Hann.
// ---------------------------------------------------------------------------
__global__ void setup_tables(float* __restrict__ tw, float* __restrict__ win) {
    int i = blockIdx.x * blockDim.x + threadIdx.x;  // 0..1023
    if (i < NFFT / 2) {
        double th = -2.0 * M_PI * (double)i / (double)NFFT;
        tw[2 * i]     = (float)cos(th);
        tw[2 * i + 1] = (float)sin(th);
    }
    if (i < NFFT) {
        double th = 2.0 * M_PI * (double)i / (double)NFFT;
        win[i] = (float)(0.5 - 0.5 * cos(th));
    }
}

// ---------------------------------------------------------------------------
// Kernel 0b: pack the sparse (triangular) mel filterbank. Each row of
// melw(80x513) is nonzero on one contiguous range; record start + KW weights
// (zero-padded tail, so a fixed-trip-count dot product is exact).
// ---------------------------------------------------------------------------
__global__ void mel_pack(const float* __restrict__ melw,
                         int* __restrict__ kstart, float* __restrict__ wpack) {
    int m = threadIdx.x;
    if (m >= NMELS) return;
    const float* row = melw + m * CUTOFF;
    int ks = 0;
    for (int k = 0; k < CUTOFF; ++k) {
        if (row[k] > 0.0f) { ks = k; break; }
    }
    kstart[m] = ks;
    for (int j = 0; j < KW; ++j) {
        int k = ks + j;
        wpack[m * KW + j] = (k < CUTOFF) ? row[k] : 0.0f;
    }
}

// ---------------------------------------------------------------------------
// Kernel 1: fused STFT -> |.| -> sparse mel -> log, 16 frames per block.
// Per pair of frames: pack as re/im of one 1024-pt complex radix-4 DIF FFT
// (5 stages, in-place; each butterfly's read-set == its write-set and the
// (j,q)->index map is bijective, so ONE barrier per stage suffices),
// conjugate-symmetry unpack to two magnitude rows in LDS, 160 sparse mel
// dot-products into an LDS melbuf. Final pass stores 80x16 outputs
// coalesced (64 B per mel row chunk).
//
// Sync audit (per pair iteration):
//   load z  -> BAR -> 5x(butterfly; BAR) -> unpack reads z, writes mag -> BAR
//   -> mel reads mag/wl, writes melbuf -> (loop) load z ...
//   * z rewrite is ordered after all z reads by the post-unpack BAR.
//   * mag rewrite (next unpack) is 6 barriers after mel reads.
//   * melbuf reads happen after the final BAR.
// ---------------------------------------------------------------------------
__global__ __launch_bounds__(256) void stft_mel(const float* __restrict__ y,
                                                const float* __restrict__ tw,
                                                const float* __restrict__ win,
                                                const int* __restrict__ kstart,
                                                const float* __restrict__ wpack,
                                                float* __restrict__ out) {
    __shared__ float2 z[NFFT + NFFT / 16];      // padded via ZIDX   8704 B
    __shared__ float2 twl[NFFT / 2];            //                   4096 B
    __shared__ float  mag0[576];                // 513 + pad         2304 B
    __shared__ float  mag1[576];                //                   2304 B
    __shared__ float  wl[NMELS * WSTRIDE];      //                  15680 B
    __shared__ float  melbuf[NMELS][TBLK + 1];  //                   5440 B
    __shared__ int    ksl[NMELS];               //                    320 B

    const int tid   = threadIdx.x;
    const int tbase = blockIdx.x * TBLK;
    const int b     = blockIdx.y;
    const float* yb = y + (size_t)b * LEN;

    // stage twiddles + packed mel weights (amortized over 8 pair-FFTs)
    for (int i = tid; i < NFFT / 2; i += 256)
        twl[i] = ((const float2*)tw)[i];
    for (int i = tid; i < NMELS * KW; i += 256)
        wl[(i / KW) * WSTRIDE + (i % KW)] = wpack[i];
    if (tid < NMELS) ksl[tid] = kstart[tid];
    if (tid < 63) { mag0[CUTOFF + tid] = 0.0f; mag1[CUTOFF + tid] = 0.0f; }

    #pragma unroll 1
    for (int p = 0; p < TBLK / 2; ++p) {
        const int t0 = tbase + 2 * p;
        const int s0 = t0 * HOP - NFFT / 2;

        // load + reflect-pad + window two frames (t0 -> re, t0+1 -> im).
        // Frames past NFRAMES are computed harmlessly (reflect indices stay
        // inside [0, LEN)) and never stored.
        for (int i = tid; i < NFFT; i += 256) {
            int p0 = s0 + i;
            int p1 = p0 + HOP;
            p0 = p0 < 0 ? -p0 : p0;  p0 = p0 >= LEN ? 2 * LEN - 2 - p0 : p0;
            p1 = p1 < 0 ? -p1 : p1;  p1 = p1 >= LEN ? 2 * LEN - 2 - p1 : p1;
            float w = win[i];
            z[ZIDX(i)] = make_float2(w * yb[p0], w * yb[p1]);
        }
        __syncthreads();

        // radix-4 DIF: M = sub-transform size, L = M/4, s = 1024/M.
        // y[j+qL] = B_q * W_M^{jq}. Output base-4 digit-reversed.
        #pragma unroll
        for (int M = NFFT, s = 1; M >= 4; M >>= 2, s <<= 2) {
            const int L   = M >> 2;
            const int j   = tid;                // 256 butterflies/stage
            const int off = j & (L - 1);
            const int i0  = ((j & ~(L - 1)) << 2) | off;

            float2 a  = z[ZIDX(i0)];
            float2 bb = z[ZIDX(i0 + L)];
            float2 c  = z[ZIDX(i0 + 2 * L)];
            float2 d  = z[ZIDX(i0 + 3 * L)];

            float2 t0v = make_float2(a.x + c.x,  a.y + c.y);
            float2 t1v = make_float2(a.x - c.x,  a.y - c.y);
            float2 t2v = make_float2(bb.x + d.x, bb.y + d.y);
            float2 t3v = make_float2(bb.x - d.x, bb.y - d.y);
            float2 mit3 = make_float2(t3v.y, -t3v.x);      // -i * t3

            float2 B0 = make_float2(t0v.x + t2v.x,  t0v.y + t2v.y);
            float2 B2 = make_float2(t0v.x - t2v.x,  t0v.y - t2v.y);
            float2 B1 = make_float2(t1v.x + mit3.x, t1v.y + mit3.y);
            float2 B3 = make_float2(t1v.x - mit3.x, t1v.y - mit3.y);

            float2 w1 = twl[off * s];          // off*s < 256
            float2 w2 = twl[2 * off * s];      // < 512: in-table
            float2 w3 = cmul(w1, w2);

            z[ZIDX(i0)]         = B0;
            z[ZIDX(i0 + L)]     = cmul(B1, w1);
            z[ZIDX(i0 + 2 * L)] = cmul(B2, w2);
            z[ZIDX(i0 + 3 * L)] = cmul(B3, w3);
            __syncthreads();
        }

        // conjugate-symmetry unpack + magnitudes.
        // Z[k] sits at base-4 digit-reversed position (k=512 -> pos 2, self-paired).
        for (int k = tid; k <= NFFT / 2; k += 256) {
            int x = k, rk = 0;
            #pragma unroll
            for (int d5 = 0; d5 < 5; ++d5) { rk = (rk << 2) | (x & 3); x >>= 2; }
            int nk = (NFFT - k) & (NFFT - 1);
            x = nk; int rnk = 0;
            #pragma unroll
            for (int d5 = 0; d5 < 5; ++d5) { rnk = (rnk << 2) | (x & 3); x >>= 2; }
            float2 Zk = z[ZIDX(rk)], Zn = z[ZIDX(rnk)];
            float f0r = 0.5f * (Zk.x + Zn.x);
            float f0i = 0.5f * (Zk.y - Zn.y);
            float f1r = 0.5f * (Zk.y + Zn.y);
            float f1i = 0.5f * (Zn.x - Zk.x);
            mag0[k] = sqrtf(f0r * f0r + f0i * f0i);
            mag1[k] = sqrtf(f1r * f1r + f1i * f1i);
        }
        __syncthreads();

        // sparse mel + log -> melbuf (stores deferred for coalescing).
        // Full unroll: constant offsets let the compiler pair adjacent
        // wl/mag reads into ds_read2_b32 (halves LDS issue slots).
        if (tid < 2 * NMELS) {
            int m = tid;
            int f = 0;
            if (m >= NMELS) { m -= NMELS; f = 1; }
            const float* mg   = f ? mag1 : mag0;
            const float* wrow = &wl[m * WSTRIDE];
            const float* mrow = &mg[ksl[m]];
            float acc = 0.0f;
            #pragma unroll
            for (int j = 0; j < KW; ++j)
                acc += wrow[j] * mrow[j];
            melbuf[m][2 * p + f] = logf(fmaxf(acc, 1e-5f));
        }
    }
    __syncthreads();

    // coalesced output: 80 rows x 16 consecutive t (64 B per row chunk)
    for (int o = tid; o < NMELS * TBLK; o += 256) {
        int m = o >> 4;
        int j = o & (TBLK - 1);
        int t = tbase + j;
        if (t < NFRAMES)
            out[((size_t)b * NMELS + m) * NFRAMES + t] = melbuf[m][j];
    }
}

// ---------------------------------------------------------------------------
extern "C" void kernel_launch(void* const* d_in, const int* in_sizes, int n_in,
                              void* d_out, int out_size, void* d_ws, size_t ws_size,
                              hipStream_t stream) {
    const float* y    = (const float*)d_in[0];
    // d_in[1] = forward_basis -- unused (FFT reproduces the windowed DFT exactly)
    const float* melw = (const float*)d_in[2];
    float* out = (float*)d_out;

    float* tw     = (float*)d_ws;            // 1024 floats (512 cplx)  4 KB
    float* win    = tw + NFFT;               // 1024 floats             4 KB
    int*   kstart = (int*)(win + NFFT);      // 80 ints (pad to 128)
    float* wpack  = (float*)(kstart + 128);  // 80*48 floats           15 KB

    setup_tables<<<4, 256, 0, stream>>>(tw, win);
    mel_pack<<<1, 128, 0, stream>>>(melw, kstart, wpack);

    dim3 g((NFRAMES + TBLK - 1) / TBLK, BATCH);   // 129 x 16 blocks
    stft_mel<<<g, 256, 0, stream>>>(y, tw, win, kstart, wpack, out);
}

// Round 7
// 173.685 us; speedup vs baseline: 1.6804x; 1.6804x over previous
//
#include <hip/hip_runtime.h>
#include <math.h>

#define HOP     256
#define CUTOFF  513
#define NMELS   80
#define BATCH   16
#define LEN     524288
#define NFRAMES 2049
#define NFFT    1024
#define KW      48              // max packed mel-filter width (analytic max ~38)
#define WSTRIDE 49              // odd LDS row stride -> conflict-free weight reads
#define TBLK    16              // frames per block (8 pair-FFTs)

// FFT LDS anti-bank-conflict padding: one extra float2 per 16
#define ZIDX(i) ((i) + ((i) >> 4))

__device__ __forceinline__ float2 cmul(float2 a, float2 b) {
    return make_float2(a.x * b.x - a.y * b.y, a.x * b.y + a.y * b.x);
}

// ---------------------------------------------------------------------------
// Kernel 0a: twiddle + window tables (d_ws is re-poisoned before every launch,
// so these must be rebuilt each call).
// tw[k] = e^{-2 pi i k/1024}, k<512 ; win = periodic Hann.
// ---------------------------------------------------------------------------
__global__ void setup_tables(float* __restrict__ tw, float* __restrict__ win) {
    int i = blockIdx.x * blockDim.x + threadIdx.x;  // 0..1023
    if (i < NFFT / 2) {
        double th = -2.0 * M_PI * (double)i / (double)NFFT;
        tw[2 * i]     = (float)cos(th);
        tw[2 * i + 1] = (float)sin(th);
    }
    if (i < NFFT) {
        double th = 2.0 * M_PI * (double)i / (double)NFFT;
        win[i] = (float)(0.5 - 0.5 * cos(th));
    }
}

// ---------------------------------------------------------------------------
// Kernel 0b: pack the sparse (triangular) mel filterbank — PARALLEL scan.
// (The round-4 serial 1-block version cost 143 us — half the total time.)
// One block per mel row; parallel first-nonzero via LDS atomicMin.
// ---------------------------------------------------------------------------
__global__ __launch_bounds__(256) void mel_pack(const float* __restrict__ melw,
                                                int* __restrict__ kstart,
                                                float* __restrict__ wpack) {
    __shared__ int smin;
    const int m = blockIdx.x;
    if (threadIdx.x == 0) smin = CUTOFF;
    __syncthreads();
    const float* row = melw + m * CUTOFF;
    int local = CUTOFF;
    for (int k = threadIdx.x; k < CUTOFF; k += 256)
        if (row[k] > 0.0f && k < local) local = k;
    atomicMin(&smin, local);
    __syncthreads();
    int ks = smin;
    if (ks >= CUTOFF) ks = 0;                     // all-zero row guard
    if (threadIdx.x == 0) kstart[m] = ks;
    for (int j = threadIdx.x; j < KW; j += 256) {
        int k = ks + j;
        wpack[m * KW + j] = (k < CUTOFF) ? row[k] : 0.0f;
    }
}

// ---------------------------------------------------------------------------
// Kernel 1: fused STFT -> |.| -> sparse mel -> log, 16 frames per block.
// Per pair of frames: pack as re/im of one 1024-pt complex radix-4 DIF FFT.
//   stage 1  : on GLOBAL loads in registers (saves an LDS round-trip+barrier)
//   stages 2-4: in-place in LDS, one barrier each
//   stage 5  : twiddles are identity (off==0) -> plain B0..B3; SCATTER to
//              natural order: value at in-place pos p=4t+q is Z[q*256+dr4(t)],
//              so write B_q -> z[q*256+dr4(t)] (bijective). Unpack reads then
//              become consecutive/conflict-free and need no index reversal.
//              (Round-4 PMC: 2.1e7 SQ_LDS_BANK_CONFLICT ~= 25% of cycles;
//              twiddle reads fixed via registers, unpack fixed here.)
// Twiddles/window are pair-invariant -> registers, loaded once per block.
// Mel phase: 80 threads compute BOTH frames per mel (weights read once).
//
// Sync audit (per pair): st1 regs->z write, BAR; st2..4 (read z/write z, BAR);
// st5 read z, BAR, scatter-write z, BAR; unpack reads z writes mag, BAR;
// mel reads mag/wl writes melbuf. Next pair's st1 z-writes sit after the
// post-unpack BAR in program order, so every thread's unpack reads complete
// first. melbuf is read only after the final barrier.
// ---------------------------------------------------------------------------
__global__ __launch_bounds__(256) void stft_mel(const float* __restrict__ y,
                                                const float* __restrict__ tw,
                                                const float* __restrict__ win,
                                                const int* __restrict__ kstart,
                                                const float* __restrict__ wpack,
                                                float* __restrict__ out) {
    __shared__ float2 z[NFFT + NFFT / 16];      // padded via ZIDX   8704 B
    __shared__ float  mag0[576];                // 513 + pad         2304 B
    __shared__ float  mag1[576];                //                   2304 B
    __shared__ float  wl[NMELS * WSTRIDE];      //                  15680 B
    __shared__ float  melbuf[NMELS][TBLK + 1];  //                   5440 B
    __shared__ int    ksl[NMELS];               //                    320 B
                                                // total            34752 B
    const int tid   = threadIdx.x;
    const int tbase = blockIdx.x * TBLK;
    const int b     = blockIdx.y;
    const float* yb = y + (size_t)b * LEN;
    const float2* twg = (const float2*)tw;

    // ---- pair-invariant registers -----------------------------------------
    // Twiddles for stages 1..4 (stage 5 twiddles are identity -> skipped).
    float2 w1r[4], w2r[4], w3r[4];
    #pragma unroll
    for (int st = 0; st < 4; ++st) {
        const int L   = 1 << (8 - 2 * st);      // 256,64,16,4
        const int s   = 1 << (2 * st);          // 1,4,16,64
        const int off = tid & (L - 1);
        float2 wa = twg[off * s];               // <= 255 in-table
        float2 wb = twg[2 * off * s];           // max 510 < 512
        w1r[st] = wa; w2r[st] = wb; w3r[st] = cmul(wa, wb);
    }
    // Window values for elements tid + 256q.
    float wreg[4];
    #pragma unroll
    for (int q = 0; q < 4; ++q) wreg[q] = win[tid + 256 * q];
    // 4-digit base-4 reversal of tid (stage-5 scatter target).
    int r4;
    {
        int x = tid, r = 0;
        #pragma unroll
        for (int d4 = 0; d4 < 4; ++d4) { r = (r << 2) | (x & 3); x >>= 2; }
        r4 = r;
    }

    // ---- LDS staging (once per block) -------------------------------------
    for (int i = tid; i < NMELS * KW; i += 256)
        wl[(i / KW) * WSTRIDE + (i % KW)] = wpack[i];
    if (tid < NMELS) ksl[tid] = kstart[tid];
    if (tid < 63) { mag0[CUTOFF + tid] = 0.0f; mag1[CUTOFF + tid] = 0.0f; }

    #pragma unroll 1
    for (int p = 0; p < TBLK / 2; ++p) {
        const int t0 = tbase + 2 * p;
        const int s0 = t0 * HOP - NFFT / 2;

        // ---- stage 1 on global loads (registers) --------------------------
        // Thread tid owns elements tid + 256q (off = tid, group = 0).
        // Frames past NFRAMES are computed harmlessly (reflect stays inside
        // [0, LEN)) and never stored.
        float2 e[4];
        #pragma unroll
        for (int q = 0; q < 4; ++q) {
            int praw = s0 + tid + 256 * q;
            int p0 = praw;
            p0 = p0 < 0 ? -p0 : p0;  p0 = p0 >= LEN ? 2 * LEN - 2 - p0 : p0;
            int p1 = praw + HOP;
            p1 = p1 < 0 ? -p1 : p1;  p1 = p1 >= LEN ? 2 * LEN - 2 - p1 : p1;
            e[q] = make_float2(wreg[q] * yb[p0], wreg[q] * yb[p1]);
        }
        {
            float2 t0v = make_float2(e[0].x + e[2].x, e[0].y + e[2].y);
            float2 t1v = make_float2(e[0].x - e[2].x, e[0].y - e[2].y);
            float2 t2v = make_float2(e[1].x + e[3].x, e[1].y + e[3].y);
            float2 t3v = make_float2(e[1].x - e[3].x, e[1].y - e[3].y);
            float2 mit3 = make_float2(t3v.y, -t3v.x);      // -i * t3
            float2 B0 = make_float2(t0v.x + t2v.x,  t0v.y + t2v.y);
            float2 B2 = make_float2(t0v.x - t2v.x,  t0v.y - t2v.y);
            float2 B1 = make_float2(t1v.x + mit3.x, t1v.y + mit3.y);
            float2 B3 = make_float2(t1v.x - mit3.x, t1v.y - mit3.y);
            z[ZIDX(tid)]        = B0;
            z[ZIDX(tid + 256)]  = cmul(B1, w1r[0]);
            z[ZIDX(tid + 512)]  = cmul(B2, w2r[0]);
            z[ZIDX(tid + 768)]  = cmul(B3, w3r[0]);
        }
        __syncthreads();

        // ---- stages 2..4 in LDS, in place ---------------------------------
        #pragma unroll
        for (int st = 1; st < 4; ++st) {
            const int L   = 1 << (8 - 2 * st);  // 64,16,4
            const int off = tid & (L - 1);
            const int i0  = ((tid & ~(L - 1)) << 2) | off;

            float2 a  = z[ZIDX(i0)];
            float2 bb = z[ZIDX(i0 + L)];
            float2 c  = z[ZIDX(i0 + 2 * L)];
            float2 d  = z[ZIDX(i0 + 3 * L)];

            float2 t0v = make_float2(a.x + c.x,  a.y + c.y);
            float2 t1v = make_float2(a.x - c.x,  a.y - c.y);
            float2 t2v = make_float2(bb.x + d.x, bb.y + d.y);
            float2 t3v = make_float2(bb.x - d.x, bb.y - d.y);
            float2 mit3 = make_float2(t3v.y, -t3v.x);      // -i * t3

            float2 B0 = make_float2(t0v.x + t2v.x,  t0v.y + t2v.y);
            float2 B2 = make_float2(t0v.x - t2v.x,  t0v.y - t2v.y);
            float2 B1 = make_float2(t1v.x + mit3.x, t1v.y + mit3.y);
            float2 B3 = make_float2(t1v.x - mit3.x, t1v.y - mit3.y);

            // in-place: this butterfly's write-set == its read-set
            z[ZIDX(i0)]         = B0;
            z[ZIDX(i0 + L)]     = cmul(B1, w1r[st]);
            z[ZIDX(i0 + 2 * L)] = cmul(B2, w2r[st]);
            z[ZIDX(i0 + 3 * L)] = cmul(B3, w3r[st]);
            __syncthreads();
        }

        // ---- stage 5: identity twiddles + scatter to NATURAL order --------
        {
            const int i0 = tid * 4;
            float2 a  = z[ZIDX(i0)];
            float2 bb = z[ZIDX(i0 + 1)];
            float2 c  = z[ZIDX(i0 + 2)];
            float2 d  = z[ZIDX(i0 + 3)];

            float2 t0v = make_float2(a.x + c.x,  a.y + c.y);
            float2 t1v = make_float2(a.x - c.x,  a.y - c.y);
            float2 t2v = make_float2(bb.x + d.x, bb.y + d.y);
            float2 t3v = make_float2(bb.x - d.x, bb.y - d.y);
            float2 mit3 = make_float2(t3v.y, -t3v.x);      // -i * t3

            float2 B0 = make_float2(t0v.x + t2v.x,  t0v.y + t2v.y);
            float2 B2 = make_float2(t0v.x - t2v.x,  t0v.y - t2v.y);
            float2 B1 = make_float2(t1v.x + mit3.x, t1v.y + mit3.y);
            float2 B3 = make_float2(t1v.x - mit3.x, t1v.y - mit3.y);

            __syncthreads();                    // all reads before any scatter
            // in-place pos p=4*tid+q holds Z[q*256 + dr4(tid)] -> natural:
            z[ZIDX(r4)]        = B0;
            z[ZIDX(r4 + 256)]  = B1;
            z[ZIDX(r4 + 512)]  = B2;
            z[ZIDX(r4 + 768)]  = B3;
            __syncthreads();
        }

        // ---- conjugate-symmetry unpack + magnitudes (natural order) -------
        for (int k = tid; k <= NFFT / 2; k += 256) {
            int nk = (NFFT - k) & (NFFT - 1);
            float2 Zk = z[ZIDX(k)], Zn = z[ZIDX(nk)];
            float f0r = 0.5f * (Zk.x + Zn.x);
            float f0i = 0.5f * (Zk.y - Zn.y);
            float f1r = 0.5f * (Zk.y + Zn.y);
            float f1i = 0.5f * (Zn.x - Zk.x);
            mag0[k] = sqrtf(f0r * f0r + f0i * f0i);
            mag1[k] = sqrtf(f1r * f1r + f1i * f1i);
        }
        __syncthreads();

        // ---- sparse mel + log -> melbuf (both frames per thread) ----------
        // wl row read ONCE, used for both frames; per-frame accumulation
        // order unchanged (bit-identical).
        if (tid < NMELS) {
            const int m = tid;
            const float* wrow = &wl[m * WSTRIDE];
            const int ks = ksl[m];
            const float* m0 = &mag0[ks];
            const float* m1 = &mag1[ks];
            float acc0 = 0.0f, acc1 = 0.0f;
            #pragma unroll
            for (int j = 0; j < KW; ++j) {
                float w = wrow[j];
                acc0 += w * m0[j];
                acc1 += w * m1[j];
            }
            melbuf[m][2 * p]     = logf(fmaxf(acc0, 1e-5f));
            melbuf[m][2 * p + 1] = logf(fmaxf(acc1, 1e-5f));
        }
    }
    __syncthreads();

    // coalesced output: 80 rows x 16 consecutive t (64 B per row chunk)
    for (int o = tid; o < NMELS * TBLK; o += 256) {
        int m = o >> 4;
        int j = o & (TBLK - 1);
        int t = tbase + j;
        if (t < NFRAMES)
            out[((size_t)b * NMELS + m) * NFRAMES + t] = melbuf[m][j];
    }
}

// ---------------------------------------------------------------------------
extern "C" void kernel_launch(void* const* d_in, const int* in_sizes, int n_in,
                              void* d_out, int out_size, void* d_ws, size_t ws_size,
                              hipStream_t stream) {
    const float* y    = (const float*)d_in[0];
    // d_in[1] = forward_basis -- unused (FFT reproduces the windowed DFT exactly)
    const float* melw = (const float*)d_in[2];
    float* out = (float*)d_out;

    float* tw     = (float*)d_ws;            // 1024 floats (512 cplx)  4 KB
    float* win    = tw + NFFT;               // 1024 floats             4 KB
    int*   kstart = (int*)(win + NFFT);      // 80 ints (pad to 128)
    float* wpack  = (float*)(kstart + 128);  // 80*48 floats           15 KB

    setup_tables<<<4, 256, 0, stream>>>(tw, win);
    mel_pack<<<NMELS, 256, 0, stream>>>(melw, kstart, wpack);

    dim3 g((NFRAMES + TBLK - 1) / TBLK, BATCH);   // 129 x 16 blocks
    stft_mel<<<g, 256, 0, stream>>>(y, tw, win, kstart, wpack, out);
}

// Round 10
// 163.625 us; speedup vs baseline: 1.7837x; 1.0615x over previous
//
#include <hip/hip_runtime.h>
#include <math.h>

#define HOP     256
#define CUTOFF  513
#define NMELS   80
#define BATCH   16
#define LEN     524288
#define NFRAMES 2049
#define NFFT    1024
#define KW      40              // max packed mel-filter width (analytic max 37: filter 79 = bins 475..511)
#define WSTRIDE 41              // odd LDS row stride -> conflict-free weight reads
#define TBLK    16              // frames per block (8 pair-FFTs)
#define NPAIRS  (TBLK / 2)
#define MAGPAD  (CUTOFF + KW - 1)   // 552: mrow overread stays in-bounds, zero-padded

// FFT LDS anti-bank-conflict padding: one extra float2 per 16
#define ZIDX(i) ((i) + ((i) >> 4))

// Full barrier that does NOT drain vmcnt (keeps prefetch loads in flight).
// LDS ops are drained (lgkmcnt) so cross-wave LDS hand-off is safe.
#define BARRIER_LDS()    asm volatile("s_waitcnt lgkmcnt(0)\n\ts_barrier" ::: "memory")
// Wave-local write->read fence for WAVE-PRIVATE LDS regions: per-wave DS-pipe
// ordering + completed writes; "memory" clobber pins compiler order.
#define FENCE_WAVE_LDS() asm volatile("s_waitcnt lgkmcnt(0)" ::: "memory")

__device__ __forceinline__ float2 cmul(float2 a, float2 b) {
    return make_float2(a.x * b.x - a.y * b.y, a.x * b.y + a.y * b.x);
}

// ---------------------------------------------------------------------------
// Kernel 0a: twiddle + window tables (d_ws is re-poisoned before every launch).
// tw[k] = e^{-2 pi i k/1024}, k<512 ; win = periodic Hann.
// ---------------------------------------------------------------------------
__global__ void setup_tables(float* __restrict__ tw, float* __restrict__ win) {
    int i = blockIdx.x * blockDim.x + threadIdx.x;  // 0..1023
    if (i < NFFT / 2) {
        double th = -2.0 * M_PI * (double)i / (double)NFFT;
        tw[2 * i]     = (float)cos(th);
        tw[2 * i + 1] = (float)sin(th);
    }
    if (i < NFFT) {
        double th = 2.0 * M_PI * (double)i / (double)NFFT;
        win[i] = (float)(0.5 - 0.5 * cos(th));
    }
}

// ---------------------------------------------------------------------------
// Kernel 0b: pack the sparse (triangular) mel filterbank — parallel scan.
// ---------------------------------------------------------------------------
__global__ __launch_bounds__(256) void mel_pack(const float* __restrict__ melw,
                                                int* __restrict__ kstart,
                                                float* __restrict__ wpack) {
    __shared__ int smin;
    const int m = blockIdx.x;
    if (threadIdx.x == 0) smin = CUTOFF;
    __syncthreads();
    const float* row = melw + m * CUTOFF;
    int local = CUTOFF;
    for (int k = threadIdx.x; k < CUTOFF; k += 256)
        if (row[k] > 0.0f && k < local) local = k;
    atomicMin(&smin, local);
    __syncthreads();
    int ks = smin;
    if (ks >= CUTOFF) ks = 0;                     // all-zero row guard
    if (threadIdx.x == 0) kstart[m] = ks;
    for (int j = threadIdx.x; j < KW; j += 256) {
        int k = ks + j;
        wpack[m * KW + j] = (k < CUTOFF) ? row[k] : 0.0f;
    }
}

// ---------------------------------------------------------------------------
// Kernel 1: fused STFT -> |.| -> sparse mel -> log, 16 frames per block.
//
// Round-7 PMC: VALUBusy 42%, Occupancy 34%, HBM 4%, conflicts 1.44e7 ->
// sync/latency-bound. This version:
//   * LDS 34.8KB -> 32.0KB (KW=40)  => 5 blocks/CU (20 waves, was 16)
//   * barriers 7 -> 4 per pair: stages 2-4 + stage-5 reads are WAVE-PRIVATE
//     (wave w only touches z[256w .. 256w+255]; verified from the index maps)
//     -> replaced by wave-local lgkmcnt fences.
//   * barriers don't drain vmcnt (hand-rolled) -> next pair's y-loads are
//     prefetched after BAR1 and stay in flight under stages 2-4.
//   * 0.5 unpack factor folded into the window registers (exact).
//
// Sync audit (per pair): st1 writes z -> BAR1 (cross-wave) -> prefetch ->
// st2..4 wave-private (fences) -> st5 reads (wave-private) -> BAR2 ->
// scatter writes z natural-order -> BAR3 -> unpack reads z, writes mag ->
// BAR4 -> mel reads mag/wl, writes melbuf (own-thread only). Next pair's
// st1 z-writes sit after BAR4. melbuf is read after the final barrier.
// All barriers are wave-uniform (no divergent barrier paths).
// ---------------------------------------------------------------------------
__global__ __launch_bounds__(256) void stft_mel(const float* __restrict__ y,
                                                const float* __restrict__ tw,
                                                const float* __restrict__ win,
                                                const int* __restrict__ kstart,
                                                const float* __restrict__ wpack,
                                                float* __restrict__ out) {
    __shared__ float2 z[NFFT + NFFT / 16];      // padded via ZIDX   8704 B
    __shared__ float  mag0[MAGPAD];             // 513 + 39 pad      2208 B
    __shared__ float  mag1[MAGPAD];             //                   2208 B
    __shared__ float  wl[NMELS * WSTRIDE];      //                  13120 B
    __shared__ float  melbuf[NMELS][TBLK + 1];  //                   5440 B
    __shared__ int    ksl[NMELS];               //                    320 B
                                                // total            32000 B  (5 blocks/CU)
    const int tid   = threadIdx.x;
    const int tbase = blockIdx.x * TBLK;
    const int b     = blockIdx.y;
    const float* yb = y + (size_t)b * LEN;
    const float2* twg = (const float2*)tw;

    // ---- pair-invariant registers -----------------------------------------
    // Twiddles for stages 1..4 (stage-5 twiddles are identity -> skipped).
    float2 w1r[4], w2r[4], w3r[4];
    #pragma unroll
    for (int st = 0; st < 4; ++st) {
        const int L   = 1 << (8 - 2 * st);      // 256,64,16,4
        const int s   = 1 << (2 * st);          // 1,4,16,64
        const int off = tid & (L - 1);
        float2 wa = twg[off * s];               // <= 255 in-table
        float2 wb = twg[2 * off * s];           // max 510 < 512
        w1r[st] = wa; w2r[st] = wb; w3r[st] = cmul(wa, wb);
    }
    // Window values (0.5 unpack factor folded in: F = (Z +- conj(Zn))/2).
    float wreg[4];
    #pragma unroll
    for (int q = 0; q < 4; ++q) wreg[q] = 0.5f * win[tid + 256 * q];
    // 4-digit base-4 reversal of tid (stage-5 scatter target).
    int r4;
    {
        int x = tid, r = 0;
        #pragma unroll
        for (int d4 = 0; d4 < 4; ++d4) { r = (r << 2) | (x & 3); x >>= 2; }
        r4 = r;
    }

    // ---- LDS staging (once per block) -------------------------------------
    for (int i = tid; i < NMELS * KW; i += 256)
        wl[(i / KW) * WSTRIDE + (i % KW)] = wpack[i];
    if (tid < NMELS) ksl[tid] = kstart[tid];
    if (tid < KW - 1) { mag0[CUTOFF + tid] = 0.0f; mag1[CUTOFF + tid] = 0.0f; }

    // ---- prefetch pair 0 --------------------------------------------------
    float pre[8];                               // raw y: [q]{frame0,frame1}
    {
        const int s0 = tbase * HOP - NFFT / 2;
        #pragma unroll
        for (int q = 0; q < 4; ++q) {
            int praw = s0 + tid + 256 * q;
            int p0 = praw;
            p0 = p0 < 0 ? -p0 : p0;  p0 = p0 >= LEN ? 2 * LEN - 2 - p0 : p0;
            int p1 = praw + HOP;
            p1 = p1 < 0 ? -p1 : p1;  p1 = p1 >= LEN ? 2 * LEN - 2 - p1 : p1;
            pre[2 * q]     = yb[p0];
            pre[2 * q + 1] = yb[p1];
        }
    }

    #pragma unroll 1
    for (int p = 0; p < NPAIRS; ++p) {
        // ---- stage 1 on prefetched values (registers) ---------------------
        // Thread tid owns elements tid + 256q. Frames past NFRAMES are
        // computed harmlessly (reflect stays in [0, LEN)) and never stored.
        {
            float2 e[4];
            #pragma unroll
            for (int q = 0; q < 4; ++q)
                e[q] = make_float2(wreg[q] * pre[2 * q], wreg[q] * pre[2 * q + 1]);
            float2 t0v = make_float2(e[0].x + e[2].x, e[0].y + e[2].y);
            float2 t1v = make_float2(e[0].x - e[2].x, e[0].y - e[2].y);
            float2 t2v = make_float2(e[1].x + e[3].x, e[1].y + e[3].y);
            float2 t3v = make_float2(e[1].x - e[3].x, e[1].y - e[3].y);
            float2 mit3 = make_float2(t3v.y, -t3v.x);      // -i * t3
            float2 B0 = make_float2(t0v.x + t2v.x,  t0v.y + t2v.y);
            float2 B2 = make_float2(t0v.x - t2v.x,  t0v.y - t2v.y);
            float2 B1 = make_float2(t1v.x + mit3.x, t1v.y + mit3.y);
            float2 B3 = make_float2(t1v.x - mit3.x, t1v.y - mit3.y);
            z[ZIDX(tid)]        = B0;
            z[ZIDX(tid + 256)]  = cmul(B1, w1r[0]);
            z[ZIDX(tid + 512)]  = cmul(B2, w2r[0]);
            z[ZIDX(tid + 768)]  = cmul(B3, w3r[0]);
        }
        BARRIER_LDS();                                     // BAR1 (cross-wave)

        // ---- prefetch next pair (hidden under stages 2-4) -----------------
        if (p + 1 < NPAIRS) {
            const int s0n = (tbase + 2 * (p + 1)) * HOP - NFFT / 2;
            #pragma unroll
            for (int q = 0; q < 4; ++q) {
                int praw = s0n + tid + 256 * q;
                int p0 = praw;
                p0 = p0 < 0 ? -p0 : p0;  p0 = p0 >= LEN ? 2 * LEN - 2 - p0 : p0;
                int p1 = praw + HOP;
                p1 = p1 < 0 ? -p1 : p1;  p1 = p1 >= LEN ? 2 * LEN - 2 - p1 : p1;
                pre[2 * q]     = yb[p0];
                pre[2 * q + 1] = yb[p1];
            }
        }

        // ---- stages 2..4: WAVE-PRIVATE in-place (wave w owns z[256w..+255])
        #pragma unroll
        for (int st = 1; st < 4; ++st) {
            const int L   = 1 << (8 - 2 * st);  // 64,16,4
            const int off = tid & (L - 1);
            const int i0  = ((tid & ~(L - 1)) << 2) | off;

            float2 a  = z[ZIDX(i0)];
            float2 bb = z[ZIDX(i0 + L)];
            float2 c  = z[ZIDX(i0 + 2 * L)];
            float2 d  = z[ZIDX(i0 + 3 * L)];

            float2 t0v = make_float2(a.x + c.x,  a.y + c.y);
            float2 t1v = make_float2(a.x - c.x,  a.y - c.y);
            float2 t2v = make_float2(bb.x + d.x, bb.y + d.y);
            float2 t3v = make_float2(bb.x - d.x, bb.y - d.y);
            float2 mit3 = make_float2(t3v.y, -t3v.x);      // -i * t3

            float2 B0 = make_float2(t0v.x + t2v.x,  t0v.y + t2v.y);
            float2 B2 = make_float2(t0v.x - t2v.x,  t0v.y - t2v.y);
            float2 B1 = make_float2(t1v.x + mit3.x, t1v.y + mit3.y);
            float2 B3 = make_float2(t1v.x - mit3.x, t1v.y - mit3.y);

            z[ZIDX(i0)]         = B0;
            z[ZIDX(i0 + L)]     = cmul(B1, w1r[st]);
            z[ZIDX(i0 + 2 * L)] = cmul(B2, w2r[st]);
            z[ZIDX(i0 + 3 * L)] = cmul(B3, w3r[st]);
            FENCE_WAVE_LDS();   // wave-local write->read hand-off
        }

        // ---- stage 5: identity twiddles + scatter to NATURAL order --------
        {
            const int i0 = tid * 4;             // reads are wave-private too
            float2 a  = z[ZIDX(i0)];
            float2 bb = z[ZIDX(i0 + 1)];
            float2 c  = z[ZIDX(i0 + 2)];
            float2 d  = z[ZIDX(i0 + 3)];

            float2 t0v = make_float2(a.x + c.x,  a.y + c.y);
            float2 t1v = make_float2(a.x - c.x,  a.y - c.y);
            float2 t2v = make_float2(bb.x + d.x, bb.y + d.y);
            float2 t3v = make_float2(bb.x - d.x, bb.y - d.y);
            float2 mit3 = make_float2(t3v.y, -t3v.x);      // -i * t3

            float2 B0 = make_float2(t0v.x + t2v.x,  t0v.y + t2v.y);
            float2 B2 = make_float2(t0v.x - t2v.x,  t0v.y - t2v.y);
            float2 B1 = make_float2(t1v.x + mit3.x, t1v.y + mit3.y);
            float2 B3 = make_float2(t1v.x - mit3.x, t1v.y - mit3.y);

            BARRIER_LDS();                      // BAR2: all reads before scatter
            // in-place pos p=4*tid+q holds Z[q*256 + dr4(tid)] -> natural:
            z[ZIDX(r4)]        = B0;
            z[ZIDX(r4 + 256)]  = B1;
            z[ZIDX(r4 + 512)]  = B2;
            z[ZIDX(r4 + 768)]  = B3;
            BARRIER_LDS();                      // BAR3: scatter visible
        }

        // ---- conjugate-symmetry unpack + magnitudes (natural order) -------
        // 0.5 already folded into the window.
        for (int k = tid; k <= NFFT / 2; k += 256) {
            int nk = (NFFT - k) & (NFFT - 1);
            float2 Zk = z[ZIDX(k)], Zn = z[ZIDX(nk)];
            float f0r = Zk.x + Zn.x;
            float f0i = Zk.y - Zn.y;
            float f1r = Zk.y + Zn.y;
            float f1i = Zn.x - Zk.x;
            mag0[k] = sqrtf(f0r * f0r + f0i * f0i);
            mag1[k] = sqrtf(f1r * f1r + f1i * f1i);
        }
        BARRIER_LDS();                          // BAR4: mag visible

        // ---- sparse mel + log -> melbuf (both frames per thread) ----------
        if (tid < NMELS) {
            const int m = tid;
            const float* wrow = &wl[m * WSTRIDE];
            const int ks = ksl[m];
            const float* m0 = &mag0[ks];
            const float* m1 = &mag1[ks];
            float acc0 = 0.0f, acc1 = 0.0f;
            #pragma unroll
            for (int j = 0; j < KW; ++j) {
                float w = wrow[j];
                acc0 += w * m0[j];
                acc1 += w * m1[j];
            }
            melbuf[m][2 * p]     = logf(fmaxf(acc0, 1e-5f));
            melbuf[m][2 * p + 1] = logf(fmaxf(acc1, 1e-5f));
        }
        // no trailing barrier: melbuf is own-thread; next st1 writes z after BAR4
    }
    BARRIER_LDS();

    // coalesced output: 80 rows x 16 consecutive t (64 B per row chunk)
    for (int o = tid; o < NMELS * TBLK; o += 256) {
        int m = o >> 4;
        int j = o & (TBLK - 1);
        int t = tbase + j;
        if (t < NFRAMES)
            out[((size_t)b * NMELS + m) * NFRAMES + t] = melbuf[m][j];
    }
}

// ---------------------------------------------------------------------------
extern "C" void kernel_launch(void* const* d_in, const int* in_sizes, int n_in,
                              void* d_out, int out_size, void* d_ws, size_t ws_size,
                              hipStream_t stream) {
    const float* y    = (const float*)d_in[0];
    // d_in[1] = forward_basis -- unused (FFT reproduces the windowed DFT exactly)
    const float* melw = (const float*)d_in[2];
    float* out = (float*)d_out;

    float* tw     = (float*)d_ws;            // 1024 floats (512 cplx)  4 KB
    float* win    = tw + NFFT;               // 1024 floats             4 KB
    int*   kstart = (int*)(win + NFFT);      // 80 ints (pad to 128)
    float* wpack  = (float*)(kstart + 128);  // 80*40 floats         12.8 KB

    setup_tables<<<4, 256, 0, stream>>>(tw, win);
    mel_pack<<<NMELS, 256, 0, stream>>>(melw, kstart, wpack);

    dim3 g((NFRAMES + TBLK - 1) / TBLK, BATCH);   // 129 x 16 blocks
    stft_mel<<<g, 256, 0, stream>>>(y, tw, win, kstart, wpack, out);
}